// Round 4
// baseline (1270.313 us; speedup 1.0000x reference)
//
#include <hip/hip_runtime.h>
#include <hip/hip_bf16.h>

#define ND 20000
#define NP 8000
#define NE 640000
#define NL 200000
#define DD 128
#define HH 256

// ---------------- CSR build ----------------
__global__ void k_hist(const int* __restrict__ src, const int* __restrict__ dst,
                       int* __restrict__ deg_d, int* __restrict__ deg_p) {
    int i = blockIdx.x * blockDim.x + threadIdx.x;
    if (i < NE) {
        atomicAdd(&deg_p[dst[i]], 1);
        atomicAdd(&deg_d[src[i]], 1);
    }
}

// single-block exclusive scan; writes rowptr[0..n] and cursor[0..n-1]
__global__ void k_scan(const int* __restrict__ deg, int* __restrict__ rowptr,
                       int* __restrict__ cursor, int n) {
    __shared__ int s[1024];
    const int t = threadIdx.x;
    const int chunk = (n + 1023) / 1024;
    const int lo = t * chunk;
    const int hi = min(n, lo + chunk);
    int local = 0;
    for (int i = lo; i < hi; ++i) local += deg[i];
    s[t] = local;
    __syncthreads();
    for (int off = 1; off < 1024; off <<= 1) {
        int v = (t >= off) ? s[t - off] : 0;
        __syncthreads();
        s[t] += v;
        __syncthreads();
    }
    int base = s[t] - local;  // exclusive prefix
    for (int i = lo; i < hi; ++i) {
        rowptr[i] = base;
        cursor[i] = base;
        base += deg[i];
    }
    if (t == 1023) rowptr[n] = s[1023];
}

__global__ void k_fill(const int* __restrict__ src, const int* __restrict__ dst,
                       int* __restrict__ cur_p, int* __restrict__ cur_d,
                       int* __restrict__ csr_p, int* __restrict__ csr_d) {
    int i = blockIdx.x * blockDim.x + threadIdx.x;
    if (i < NE) {
        int s = src[i], d = dst[i];
        csr_p[atomicAdd(&cur_p[d], 1)] = s;   // per protein: drug ids
        csr_d[atomicAdd(&cur_d[s], 1)] = d;   // per drug: protein ids
    }
}

// ---------------- CSR aggregate: one block per dst node ----------------
template <int F>
__global__ void k_aggregate(const float* __restrict__ x, const int* __restrict__ rowptr,
                            const int* __restrict__ idx, float* __restrict__ agg) {
    const int b = blockIdx.x;
    const int t = threadIdx.x;
    const int start = rowptr[b], end = rowptr[b + 1];
    float a0 = 0.f, a1 = 0.f, a2 = 0.f, a3 = 0.f;
    int j = start;
    for (; j + 3 < end; j += 4) {
        int r0 = idx[j], r1 = idx[j + 1], r2 = idx[j + 2], r3 = idx[j + 3];
        a0 += x[r0 * F + t];
        a1 += x[r1 * F + t];
        a2 += x[r2 * F + t];
        a3 += x[r3 * F + t];
    }
    for (; j < end; ++j) a0 += x[idx[j] * F + t];
    agg[b * F + t] = (a0 + a1) + (a2 + a3);
}

// ---------------- fused f32 GEMM: out = A1@W1 [+ A2@W2] [+ bias] [tanh] ----------------
// N fixed = 256. BM=64, BN=64, BK=32, 256 threads, 4x4 microtile.
#define BM 64
#define BN 64
#define BKK 32

__global__ __launch_bounds__(256)
void k_gemm(int n, int K,
            const float* __restrict__ A1, const float* __restrict__ W1,
            const float* __restrict__ A2, const float* __restrict__ W2,
            const float* __restrict__ bias, float* __restrict__ out, int act) {
    __shared__ __align__(16) float As[BKK][BM + 4];  // k-major, stride 68 keeps 16B align
    __shared__ __align__(16) float Bs[BKK][BN];

    const int tid = threadIdx.x;
    const int tr = tid >> 4;   // 0..15
    const int tc = tid & 15;   // 0..15
    const int row0 = blockIdx.x * BM;
    const int col0 = blockIdx.y * BN;

    float acc[4][4] = {};

    for (int pass = 0; pass < 2; ++pass) {
        const float* A = pass ? A2 : A1;
        const float* W = pass ? W2 : W1;
        if (A == nullptr) continue;
        for (int k0 = 0; k0 < K; k0 += BKK) {
            // A tile: 64 rows x 32 k, store transposed As[k][row]
            {
                const int lr = tid >> 3;          // 0..31
                const int lc = (tid & 7) * 4;     // 0..28
#pragma unroll
                for (int h = 0; h < 2; ++h) {
                    const int row = lr + 32 * h;
                    const int grow = row0 + row;
                    float4 v = make_float4(0.f, 0.f, 0.f, 0.f);
                    if (grow < n) v = *(const float4*)(A + (size_t)grow * K + k0 + lc);
                    As[lc + 0][row] = v.x;
                    As[lc + 1][row] = v.y;
                    As[lc + 2][row] = v.z;
                    As[lc + 3][row] = v.w;
                }
                // B tile: 32 k-rows x 64 cols
                const int br = tid >> 4;          // 0..15
                const int bc = (tid & 15) * 4;    // 0..60
#pragma unroll
                for (int h = 0; h < 2; ++h) {
                    const int krow = br + 16 * h;
                    *(float4*)&Bs[krow][bc] =
                        *(const float4*)(W + (size_t)(k0 + krow) * HH + col0 + bc);
                }
            }
            __syncthreads();
#pragma unroll
            for (int k = 0; k < BKK; ++k) {
                const float4 av = *(const float4*)&As[k][tr * 4];
                const float4 bv = *(const float4*)&Bs[k][tc * 4];
                const float a[4] = {av.x, av.y, av.z, av.w};
                const float b[4] = {bv.x, bv.y, bv.z, bv.w};
#pragma unroll
                for (int i = 0; i < 4; ++i)
#pragma unroll
                    for (int j = 0; j < 4; ++j) acc[i][j] += a[i] * b[j];
            }
            __syncthreads();
        }
    }

    float bv[4] = {0.f, 0.f, 0.f, 0.f};
    if (bias) {
        const float4 b4 = *(const float4*)(bias + col0 + tc * 4);
        bv[0] = b4.x; bv[1] = b4.y; bv[2] = b4.z; bv[3] = b4.w;
    }
#pragma unroll
    for (int i = 0; i < 4; ++i) {
        const int grow = row0 + tr * 4 + i;
        if (grow < n) {
            float vals[4];
#pragma unroll
            for (int j = 0; j < 4; ++j) {
                float v = acc[i][j] + bv[j];
                if (act == 1) v = tanhf(v);
                vals[j] = v;
            }
            *(float4*)(out + (size_t)grow * HH + col0 + tc * 4) =
                make_float4(vals[0], vals[1], vals[2], vals[3]);
        }
    }
}

// ---------------- link decoder: one wave per link ----------------
__global__ void k_decode(const float* __restrict__ Ab, const float* __restrict__ Bb,
                         const int* __restrict__ rows, const int* __restrict__ cols,
                         const float* __restrict__ W2, const float* __restrict__ b2,
                         float* __restrict__ out) {
    const int wid = (blockIdx.x * blockDim.x + threadIdx.x) >> 6;
    const int lane = threadIdx.x & 63;
    if (wid >= NL) return;
    const int r = rows[wid], c = cols[wid];
    const float4 a = *(const float4*)(Ab + (size_t)r * HH + lane * 4);
    const float4 b = *(const float4*)(Bb + (size_t)c * HH + lane * 4);
    const float4 w = *(const float4*)(W2 + lane * 4);
    float s = fmaxf(a.x + b.x, 0.f) * w.x + fmaxf(a.y + b.y, 0.f) * w.y +
              fmaxf(a.z + b.z, 0.f) * w.z + fmaxf(a.w + b.w, 0.f) * w.w;
#pragma unroll
    for (int off = 32; off > 0; off >>= 1) s += __shfl_xor(s, off, 64);
    if (lane == 0) out[wid] = s + b2[0];
}

extern "C" void kernel_launch(void* const* d_in, const int* in_sizes, int n_in,
                              void* d_out, int out_size, void* d_ws, size_t ws_size,
                              hipStream_t stream) {
    const float* x_drug  = (const float*)d_in[0];
    const float* x_prot  = (const float*)d_in[1];
    const int*   ei_src  = (const int*)d_in[2];
    const int*   ei_dst  = (const int*)d_in[3];
    const int*   eli_row = (const int*)d_in[4];
    const int*   eli_col = (const int*)d_in[5];
    const float* Wl_in_dp  = (const float*)d_in[6];
    const float* bl_in_dp  = (const float*)d_in[7];
    const float* Wr_in_dp  = (const float*)d_in[8];
    const float* Wl_in_pd  = (const float*)d_in[9];
    const float* bl_in_pd  = (const float*)d_in[10];
    const float* Wr_in_pd  = (const float*)d_in[11];
    const float* Wl_med_dp = (const float*)d_in[12];
    const float* bl_med_dp = (const float*)d_in[13];
    const float* Wr_med_dp = (const float*)d_in[14];
    const float* Wl_med_pd = (const float*)d_in[15];
    const float* bl_med_pd = (const float*)d_in[16];
    const float* Wr_med_pd = (const float*)d_in[17];
    const float* Wl_out_dp = (const float*)d_in[18];
    const float* bl_out_dp = (const float*)d_in[19];
    const float* Wr_out_dp = (const float*)d_in[20];
    const float* Wl_out_pd = (const float*)d_in[21];
    const float* bl_out_pd = (const float*)d_in[22];
    const float* Wr_out_pd = (const float*)d_in[23];
    const float* W1 = (const float*)d_in[24];
    const float* b1 = (const float*)d_in[25];
    const float* W2 = (const float*)d_in[26];
    const float* b2 = (const float*)d_in[27];

    char* ws = (char*)d_ws;
    size_t off = 0;
    auto alloc = [&](size_t bytes) {
        void* p = ws + off;
        off = (off + bytes + 255) & ~(size_t)255;
        return p;
    };

    int* deg_p    = (int*)alloc((size_t)NP * 4);
    int* deg_d    = (int*)alloc((size_t)ND * 4);
    int* rowptr_p = (int*)alloc((size_t)(NP + 1) * 4);
    int* rowptr_d = (int*)alloc((size_t)(ND + 1) * 4);
    int* cur_p    = (int*)alloc((size_t)NP * 4);
    int* cur_d    = (int*)alloc((size_t)ND * 4);
    int* csr_p    = (int*)alloc((size_t)NE * 4);
    int* csr_d    = (int*)alloc((size_t)NE * 4);
    float* xd0  = (float*)alloc((size_t)ND * HH * 4);
    float* xd1  = (float*)alloc((size_t)ND * HH * 4);
    float* xp0  = (float*)alloc((size_t)NP * HH * 4);
    float* xp1  = (float*)alloc((size_t)NP * HH * 4);
    float* aggd = (float*)alloc((size_t)ND * HH * 4);  // reused as decoder A-buf
    float* aggp = (float*)alloc((size_t)NP * HH * 4);  // reused as decoder B-buf

    float* zd   = (float*)d_out;
    float* zp   = zd + (size_t)ND * HH;
    float* outv = zp + (size_t)NP * HH;

    const dim3 gD((ND + BM - 1) / BM, HH / BN);   // 313 x 4
    const dim3 gP((NP + BM - 1) / BM, HH / BN);   // 125 x 4

    // ---- CSR build (once per launch; reused for all 4 layers) ----
    hipMemsetAsync(deg_p, 0, (size_t)NP * 4, stream);
    hipMemsetAsync(deg_d, 0, (size_t)ND * 4, stream);
    k_hist<<<(NE + 255) / 256, 256, 0, stream>>>(ei_src, ei_dst, deg_d, deg_p);
    k_scan<<<1, 1024, 0, stream>>>(deg_p, rowptr_p, cur_p, NP);
    k_scan<<<1, 1024, 0, stream>>>(deg_d, rowptr_d, cur_d, ND);
    k_fill<<<(NE + 255) / 256, 256, 0, stream>>>(ei_src, ei_dst, cur_p, cur_d, csr_p, csr_d);

    // ---- layer in (K=128), tanh ----
    k_aggregate<DD><<<NP, DD, 0, stream>>>(x_drug, rowptr_p, csr_p, aggp);
    k_aggregate<DD><<<ND, DD, 0, stream>>>(x_prot, rowptr_d, csr_d, aggd);
    k_gemm<<<gP, 256, 0, stream>>>(NP, DD, aggp, Wl_in_dp, x_prot, Wr_in_dp, bl_in_dp, xp1, 1);
    k_gemm<<<gD, 256, 0, stream>>>(ND, DD, aggd, Wl_in_pd, x_drug, Wr_in_pd, bl_in_pd, xd1, 1);

    // ---- med layer 1: (xd1,xp1) -> (xd0,xp0), tanh ----
    k_aggregate<HH><<<NP, HH, 0, stream>>>(xd1, rowptr_p, csr_p, aggp);
    k_aggregate<HH><<<ND, HH, 0, stream>>>(xp1, rowptr_d, csr_d, aggd);
    k_gemm<<<gP, 256, 0, stream>>>(NP, HH, aggp, Wl_med_dp, xp1, Wr_med_dp, bl_med_dp, xp0, 1);
    k_gemm<<<gD, 256, 0, stream>>>(ND, HH, aggd, Wl_med_pd, xd1, Wr_med_pd, bl_med_pd, xd0, 1);

    // ---- med layer 2: (xd0,xp0) -> (xd1,xp1), tanh ----
    k_aggregate<HH><<<NP, HH, 0, stream>>>(xd0, rowptr_p, csr_p, aggp);
    k_aggregate<HH><<<ND, HH, 0, stream>>>(xp0, rowptr_d, csr_d, aggd);
    k_gemm<<<gP, 256, 0, stream>>>(NP, HH, aggp, Wl_med_dp, xp0, Wr_med_dp, bl_med_dp, xp1, 1);
    k_gemm<<<gD, 256, 0, stream>>>(ND, HH, aggd, Wl_med_pd, xd0, Wr_med_pd, bl_med_pd, xd1, 1);

    // ---- layer out: (xd1,xp1) -> (zd,zp), no act ----
    k_aggregate<HH><<<NP, HH, 0, stream>>>(xd1, rowptr_p, csr_p, aggp);
    k_aggregate<HH><<<ND, HH, 0, stream>>>(xp1, rowptr_d, csr_d, aggd);
    k_gemm<<<gP, 256, 0, stream>>>(NP, HH, aggp, Wl_out_dp, xp1, Wr_out_dp, bl_out_dp, zp, 0);
    k_gemm<<<gD, 256, 0, stream>>>(ND, HH, aggd, Wl_out_pd, xd1, Wr_out_pd, bl_out_pd, zd, 0);

    // ---- decoder: A = zd@W1_top, B = zp@W1_bot + b1, then per-link relu-dot ----
    k_gemm<<<gD, 256, 0, stream>>>(ND, HH, zd, W1, nullptr, nullptr, nullptr, aggd, 0);
    k_gemm<<<gP, 256, 0, stream>>>(NP, HH, zp, W1 + (size_t)HH * HH, nullptr, nullptr, b1, aggp, 0);
    k_decode<<<(NL + 3) / 4, 256, 0, stream>>>(aggd, aggp, eli_row, eli_col, W2, b2, outv);
}

// Round 11
// 750.634 us; speedup vs baseline: 1.6923x; 1.6923x over previous
//
#include <hip/hip_runtime.h>
#include <hip/hip_bf16.h>

#define ND 20000
#define NP 8000
#define NE 640000
#define NL 200000
#define DD 128
#define HH 256

typedef __attribute__((ext_vector_type(8))) short short8;
typedef __attribute__((ext_vector_type(4))) float f32x4;

__device__ inline float bflo(unsigned int u) {
    union { unsigned int u; float f; } x; x.u = u << 16; return x.f;
}
__device__ inline float bfhi(unsigned int u) {
    union { unsigned int u; float f; } x; x.u = u & 0xffff0000u; return x.f;
}
__device__ inline unsigned short f2b(float f) {  // RNE f32->bf16
    union { float f; unsigned int u; } x; x.f = f;
    unsigned int r = x.u + 0x7fffu + ((x.u >> 16) & 1u);
    return (unsigned short)(r >> 16);
}

// ---------------- CSR build (unchanged, proven) ----------------
__global__ void k_hist(const int* __restrict__ src, const int* __restrict__ dst,
                       int* __restrict__ deg_d, int* __restrict__ deg_p) {
    int i = blockIdx.x * blockDim.x + threadIdx.x;
    if (i < NE) {
        atomicAdd(&deg_p[dst[i]], 1);
        atomicAdd(&deg_d[src[i]], 1);
    }
}

__global__ void k_scan(const int* __restrict__ deg, int* __restrict__ rowptr,
                       int* __restrict__ cursor, int n) {
    __shared__ int s[1024];
    const int t = threadIdx.x;
    const int chunk = (n + 1023) / 1024;
    const int lo = t * chunk;
    const int hi = min(n, lo + chunk);
    int local = 0;
    for (int i = lo; i < hi; ++i) local += deg[i];
    s[t] = local;
    __syncthreads();
    for (int off = 1; off < 1024; off <<= 1) {
        int v = (t >= off) ? s[t - off] : 0;
        __syncthreads();
        s[t] += v;
        __syncthreads();
    }
    int base = s[t] - local;
    for (int i = lo; i < hi; ++i) {
        rowptr[i] = base;
        cursor[i] = base;
        base += deg[i];
    }
    if (t == 1023) rowptr[n] = s[1023];
}

__global__ void k_fill(const int* __restrict__ src, const int* __restrict__ dst,
                       int* __restrict__ cur_p, int* __restrict__ cur_d,
                       int* __restrict__ csr_p, int* __restrict__ csr_d) {
    int i = blockIdx.x * blockDim.x + threadIdx.x;
    if (i < NE) {
        int s = src[i], d = dst[i];
        csr_p[atomicAdd(&cur_p[d], 1)] = s;
        csr_d[atomicAdd(&cur_d[s], 1)] = d;
    }
}

// ---------------- f32 -> bf16 convert (vectorized) ----------------
__global__ void k_f2b(const float* __restrict__ in, unsigned short* __restrict__ out, int n4) {
    int i = blockIdx.x * blockDim.x + threadIdx.x;
    if (i < n4) {
        float4 v = ((const float4*)in)[i];
        ushort4 o;
        o.x = f2b(v.x); o.y = f2b(v.y); o.z = f2b(v.z); o.w = f2b(v.w);
        ((ushort4*)out)[i] = o;
    }
}

// ---------------- weight transpose+convert: dst[n][k] = bf16(src[k][n]) ----------------
struct WtD { const float* src; unsigned short* dst; int kbits; };
struct WtPack { WtD d[14]; };
__global__ void k_wt(WtPack p) {
    WtD d = p.d[blockIdx.y];
    const int K = 1 << d.kbits;
    int i = blockIdx.x * blockDim.x + threadIdx.x;
    if (i < 256 * K) {
        int nn = i >> d.kbits, k = i & (K - 1);
        d.dst[i] = f2b(d.src[k * 256 + nn]);
    }
}

// ---------------- bf16 CSR aggregates: 1 wave per dst node ----------------
__global__ void k_agg128(const unsigned short* __restrict__ x, const int* __restrict__ rowptr,
                         const int* __restrict__ idx, unsigned short* __restrict__ agg) {
    const int b = blockIdx.x, t = threadIdx.x;  // 64 threads, 2 feats/thread
    const int s = rowptr[b], e = rowptr[b + 1];
    float a0 = 0.f, a1 = 0.f;
    int j = s;
    for (; j + 1 < e; j += 2) {
        unsigned int u = *(const unsigned int*)(x + (size_t)idx[j] * 128 + 2 * t);
        unsigned int v = *(const unsigned int*)(x + (size_t)idx[j + 1] * 128 + 2 * t);
        a0 += bflo(u) + bflo(v);
        a1 += bfhi(u) + bfhi(v);
    }
    if (j < e) {
        unsigned int u = *(const unsigned int*)(x + (size_t)idx[j] * 128 + 2 * t);
        a0 += bflo(u); a1 += bfhi(u);
    }
    agg[(size_t)b * 128 + 2 * t]     = f2b(a0);
    agg[(size_t)b * 128 + 2 * t + 1] = f2b(a1);
}

__global__ void k_agg256(const unsigned short* __restrict__ x, const int* __restrict__ rowptr,
                         const int* __restrict__ idx, unsigned short* __restrict__ agg) {
    const int b = blockIdx.x, t = threadIdx.x;  // 64 threads, 4 feats/thread
    const int s = rowptr[b], e = rowptr[b + 1];
    float a0 = 0.f, a1 = 0.f, a2 = 0.f, a3 = 0.f;
    int j = s;
    for (; j + 1 < e; j += 2) {
        uint2 u = *(const uint2*)(x + (size_t)idx[j] * 256 + 4 * t);
        uint2 v = *(const uint2*)(x + (size_t)idx[j + 1] * 256 + 4 * t);
        a0 += bflo(u.x) + bflo(v.x);
        a1 += bfhi(u.x) + bfhi(v.x);
        a2 += bflo(u.y) + bflo(v.y);
        a3 += bfhi(u.y) + bfhi(v.y);
    }
    if (j < e) {
        uint2 u = *(const uint2*)(x + (size_t)idx[j] * 256 + 4 * t);
        a0 += bflo(u.x); a1 += bfhi(u.x); a2 += bflo(u.y); a3 += bfhi(u.y);
    }
    agg[(size_t)b * 256 + 4 * t]     = f2b(a0);
    agg[(size_t)b * 256 + 4 * t + 1] = f2b(a1);
    agg[(size_t)b * 256 + 4 * t + 2] = f2b(a2);
    agg[(size_t)b * 256 + 4 * t + 3] = f2b(a3);
}

// ---------------- MFMA bf16 GEMM: out = A1@W1 [+ A2@W2] [+bias] [tanh] ----------------
// BM=64, BN=128 (grid.y=2 over N=256), BK=32, 256 threads = 4 waves.
// A/B frag: lane l holds elem [m=l&15][k=8*(l>>4)+e]; D: [row=4*(l>>4)+r][col=l&15].
__global__ __launch_bounds__(256)
void k_mgemm(int n,
             const unsigned short* __restrict__ A1, const unsigned short* __restrict__ W1t, int K1,
             const unsigned short* __restrict__ A2, const unsigned short* __restrict__ W2t, int K2,
             const float* __restrict__ bias, float* __restrict__ outF,
             unsigned short* __restrict__ outB, int act) {
    __shared__ short As[64][40];    // +8 pad: 80B row stride avoids b128 bank conflicts
    __shared__ short Bs[128][40];

    const int tid = threadIdx.x;
    const int w = tid >> 6, l = tid & 63;
    const int m16 = l & 15, kg = l >> 4;
    const int row0 = blockIdx.x * 64;
    const int col0 = blockIdx.y * 128;

    const f32x4 z4 = {0.f, 0.f, 0.f, 0.f};
    f32x4 acc[4][2];
#pragma unroll
    for (int i = 0; i < 4; ++i)
#pragma unroll
        for (int j = 0; j < 2; ++j) acc[i][j] = z4;

    for (int pass = 0; pass < 2; ++pass) {
        const unsigned short* A  = pass ? A2 : A1;
        const unsigned short* Wt = pass ? W2t : W1t;
        const int K = pass ? K2 : K1;
        if (A == nullptr) continue;
        for (int k0 = 0; k0 < K; k0 += 32) {
            {
                const int ar = tid >> 2, ac = (tid & 3) * 8;
                const int gr = row0 + ar;
                short8 v = {0, 0, 0, 0, 0, 0, 0, 0};
                if (gr < n) v = *(const short8*)(A + (size_t)gr * K + k0 + ac);
                *(short8*)&As[ar][ac] = v;
                *(short8*)&Bs[ar][ac] =
                    *(const short8*)(Wt + (size_t)(col0 + ar) * K + k0 + ac);
                *(short8*)&Bs[ar + 64][ac] =
                    *(const short8*)(Wt + (size_t)(col0 + ar + 64) * K + k0 + ac);
            }
            __syncthreads();
            short8 af[4];
#pragma unroll
            for (int i = 0; i < 4; ++i) af[i] = *(const short8*)&As[16 * i + m16][8 * kg];
#pragma unroll
            for (int j = 0; j < 2; ++j) {
                short8 bf = *(const short8*)&Bs[32 * w + 16 * j + m16][8 * kg];
#pragma unroll
                for (int i = 0; i < 4; ++i)
                    acc[i][j] = __builtin_amdgcn_mfma_f32_16x16x32_bf16(af[i], bf, acc[i][j], 0, 0, 0);
            }
            __syncthreads();
        }
    }

#pragma unroll
    for (int j = 0; j < 2; ++j) {
        const int gc = col0 + 32 * w + 16 * j + m16;
        const float bv = bias ? bias[gc] : 0.f;
#pragma unroll
        for (int i = 0; i < 4; ++i) {
#pragma unroll
            for (int r = 0; r < 4; ++r) {
                const int gr = row0 + 16 * i + 4 * kg + r;
                if (gr < n) {
                    float v = acc[i][j][r] + bv;
                    if (act) v = tanhf(v);
                    if (outF) outF[(size_t)gr * HH + gc] = v;
                    if (outB) outB[(size_t)gr * HH + gc] = f2b(v);
                }
            }
        }
    }
}

// ---------------- link decoder: one wave per link, bf16 pair-gather ----------------
__global__ void k_decode(const unsigned short* __restrict__ Ab, const unsigned short* __restrict__ Bb,
                         const int* __restrict__ rows, const int* __restrict__ cols,
                         const float* __restrict__ W2, const float* __restrict__ b2,
                         float* __restrict__ out) {
    const int wid = (blockIdx.x * blockDim.x + threadIdx.x) >> 6;
    const int lane = threadIdx.x & 63;
    if (wid >= NL) return;
    const int r = rows[wid], c = cols[wid];
    uint2 ua = *(const uint2*)(Ab + (size_t)r * HH + 4 * lane);
    uint2 ub = *(const uint2*)(Bb + (size_t)c * HH + 4 * lane);
    float4 wv = *(const float4*)(W2 + 4 * lane);
    float s = fmaxf(bflo(ua.x) + bflo(ub.x), 0.f) * wv.x +
              fmaxf(bfhi(ua.x) + bfhi(ub.x), 0.f) * wv.y +
              fmaxf(bflo(ua.y) + bflo(ub.y), 0.f) * wv.z +
              fmaxf(bfhi(ua.y) + bfhi(ub.y), 0.f) * wv.w;
#pragma unroll
    for (int off = 32; off > 0; off >>= 1) s += __shfl_xor(s, off, 64);
    if (lane == 0) out[wid] = s + b2[0];
}

extern "C" void kernel_launch(void* const* d_in, const int* in_sizes, int n_in,
                              void* d_out, int out_size, void* d_ws, size_t ws_size,
                              hipStream_t stream) {
    const float* x_drug  = (const float*)d_in[0];
    const float* x_prot  = (const float*)d_in[1];
    const int*   ei_src  = (const int*)d_in[2];
    const int*   ei_dst  = (const int*)d_in[3];
    const int*   eli_row = (const int*)d_in[4];
    const int*   eli_col = (const int*)d_in[5];
    const float* Wl_in_dp  = (const float*)d_in[6];
    const float* bl_in_dp  = (const float*)d_in[7];
    const float* Wr_in_dp  = (const float*)d_in[8];
    const float* Wl_in_pd  = (const float*)d_in[9];
    const float* bl_in_pd  = (const float*)d_in[10];
    const float* Wr_in_pd  = (const float*)d_in[11];
    const float* Wl_med_dp = (const float*)d_in[12];
    const float* bl_med_dp = (const float*)d_in[13];
    const float* Wr_med_dp = (const float*)d_in[14];
    const float* Wl_med_pd = (const float*)d_in[15];
    const float* bl_med_pd = (const float*)d_in[16];
    const float* Wr_med_pd = (const float*)d_in[17];
    const float* Wl_out_dp = (const float*)d_in[18];
    const float* bl_out_dp = (const float*)d_in[19];
    const float* Wr_out_dp = (const float*)d_in[20];
    const float* Wl_out_pd = (const float*)d_in[21];
    const float* bl_out_pd = (const float*)d_in[22];
    const float* Wr_out_pd = (const float*)d_in[23];
    const float* W1 = (const float*)d_in[24];
    const float* b1 = (const float*)d_in[25];
    const float* W2 = (const float*)d_in[26];
    const float* b2 = (const float*)d_in[27];

    char* ws = (char*)d_ws;
    size_t off = 0;
    auto alloc = [&](size_t bytes) {
        void* p = ws + off;
        off = (off + bytes + 255) & ~(size_t)255;
        return p;
    };

    int* deg_p    = (int*)alloc((size_t)NP * 4);
    int* deg_d    = (int*)alloc((size_t)ND * 4);
    int* rowptr_p = (int*)alloc((size_t)(NP + 1) * 4);
    int* rowptr_d = (int*)alloc((size_t)(ND + 1) * 4);
    int* cur_p    = (int*)alloc((size_t)NP * 4);
    int* cur_d    = (int*)alloc((size_t)ND * 4);
    int* csr_p    = (int*)alloc((size_t)NE * 4);
    int* csr_d    = (int*)alloc((size_t)NE * 4);

    unsigned short* wt[14];
    const int kk[14] = {128,128,128,128, 256,256,256,256, 256,256,256,256, 256,256};
    for (int i = 0; i < 14; ++i) wt[i] = (unsigned short*)alloc((size_t)256 * kk[i] * 2);

    unsigned short* xdbf = (unsigned short*)alloc((size_t)ND * DD * 2);
    unsigned short* xpbf = (unsigned short*)alloc((size_t)NP * DD * 2);
    unsigned short* xd_a = (unsigned short*)alloc((size_t)ND * HH * 2);
    unsigned short* xd_b = (unsigned short*)alloc((size_t)ND * HH * 2);
    unsigned short* xp_a = (unsigned short*)alloc((size_t)NP * HH * 2);
    unsigned short* xp_b = (unsigned short*)alloc((size_t)NP * HH * 2);
    unsigned short* aggd = (unsigned short*)alloc((size_t)ND * HH * 2);
    unsigned short* aggp = (unsigned short*)alloc((size_t)NP * HH * 2);
    unsigned short* zdbf = (unsigned short*)alloc((size_t)ND * HH * 2);
    unsigned short* zpbf = (unsigned short*)alloc((size_t)NP * HH * 2);

    float* zd   = (float*)d_out;
    float* zp   = zd + (size_t)ND * HH;
    float* outv = zp + (size_t)NP * HH;

    const dim3 gD((ND + 63) / 64, 2);   // 313 x 2
    const dim3 gP((NP + 63) / 64, 2);   // 125 x 2

    // ---- CSR build ----
    hipMemsetAsync(deg_p, 0, (size_t)NP * 4, stream);
    hipMemsetAsync(deg_d, 0, (size_t)ND * 4, stream);
    k_hist<<<(NE + 255) / 256, 256, 0, stream>>>(ei_src, ei_dst, deg_d, deg_p);
    k_scan<<<1, 1024, 0, stream>>>(deg_p, rowptr_p, cur_p, NP);
    k_scan<<<1, 1024, 0, stream>>>(deg_d, rowptr_d, cur_d, ND);
    k_fill<<<(NE + 255) / 256, 256, 0, stream>>>(ei_src, ei_dst, cur_p, cur_d, csr_p, csr_d);

    // ---- input/weight conversion ----
    k_f2b<<<(ND * DD / 4 + 255) / 256, 256, 0, stream>>>(x_drug, xdbf, ND * DD / 4);
    k_f2b<<<(NP * DD / 4 + 255) / 256, 256, 0, stream>>>(x_prot, xpbf, NP * DD / 4);
    {
        WtPack p;
        const float* src[14] = {Wl_in_dp, Wr_in_dp, Wl_in_pd, Wr_in_pd,
                                Wl_med_dp, Wr_med_dp, Wl_med_pd, Wr_med_pd,
                                Wl_out_dp, Wr_out_dp, Wl_out_pd, Wr_out_pd,
                                W1, W1 + (size_t)HH * HH};
        for (int i = 0; i < 14; ++i) {
            p.d[i].src = src[i];
            p.d[i].dst = wt[i];
            p.d[i].kbits = (kk[i] == 128) ? 7 : 8;
        }
        k_wt<<<dim3(256, 14), 256, 0, stream>>>(p);
    }

    // ---- layer in (K=128), tanh -> xp_a/xd_a ----
    k_agg128<<<NP, 64, 0, stream>>>(xdbf, rowptr_p, csr_p, aggp);
    k_agg128<<<ND, 64, 0, stream>>>(xpbf, rowptr_d, csr_d, aggd);
    k_mgemm<<<gP, 256, 0, stream>>>(NP, aggp, wt[0], 128, xpbf, wt[1], 128, bl_in_dp, nullptr, xp_a, 1);
    k_mgemm<<<gD, 256, 0, stream>>>(ND, aggd, wt[2], 128, xdbf, wt[3], 128, bl_in_pd, nullptr, xd_a, 1);

    // ---- med layer 1 -> xp_b/xd_b ----
    k_agg256<<<NP, 64, 0, stream>>>(xd_a, rowptr_p, csr_p, aggp);
    k_agg256<<<ND, 64, 0, stream>>>(xp_a, rowptr_d, csr_d, aggd);
    k_mgemm<<<gP, 256, 0, stream>>>(NP, aggp, wt[4], 256, xp_a, wt[5], 256, bl_med_dp, nullptr, xp_b, 1);
    k_mgemm<<<gD, 256, 0, stream>>>(ND, aggd, wt[6], 256, xd_a, wt[7], 256, bl_med_pd, nullptr, xd_b, 1);

    // ---- med layer 2 -> xp_a/xd_a ----
    k_agg256<<<NP, 64, 0, stream>>>(xd_b, rowptr_p, csr_p, aggp);
    k_agg256<<<ND, 64, 0, stream>>>(xp_b, rowptr_d, csr_d, aggd);
    k_mgemm<<<gP, 256, 0, stream>>>(NP, aggp, wt[4], 256, xp_b, wt[5], 256, bl_med_dp, nullptr, xp_a, 1);
    k_mgemm<<<gD, 256, 0, stream>>>(ND, aggd, wt[6], 256, xd_b, wt[7], 256, bl_med_pd, nullptr, xd_a, 1);

    // ---- layer out (no act): f32 -> d_out, bf16 -> zdbf/zpbf ----
    k_agg256<<<NP, 64, 0, stream>>>(xd_a, rowptr_p, csr_p, aggp);
    k_agg256<<<ND, 64, 0, stream>>>(xp_a, rowptr_d, csr_d, aggd);
    k_mgemm<<<gP, 256, 0, stream>>>(NP, aggp, wt[8], 256, xp_a, wt[9], 256, bl_out_dp, zp, zpbf, 0);
    k_mgemm<<<gD, 256, 0, stream>>>(ND, aggd, wt[10], 256, xd_a, wt[11], 256, bl_out_pd, zd, zdbf, 0);

    // ---- decoder: A = zd@W1_top -> xd_b, B = zp@W1_bot + b1 -> xp_b (relu in k_decode) ----
    k_mgemm<<<gD, 256, 0, stream>>>(ND, zdbf, wt[12], 256, nullptr, nullptr, 0,
                                    nullptr, nullptr, xd_b, 0);
    k_mgemm<<<gP, 256, 0, stream>>>(NP, zpbf, wt[13], 256, nullptr, nullptr, 0,
                                    b1, nullptr, xp_b, 0);
    k_decode<<<(NL + 3) / 4, 256, 0, stream>>>(xd_b, xp_b, eli_row, eli_col, W2, b2, outv);
}

// Round 14
// 683.913 us; speedup vs baseline: 1.8574x; 1.0976x over previous
//
#include <hip/hip_runtime.h>
#include <hip/hip_bf16.h>

#define ND 20000
#define NP 8000
#define NE 640000
#define NL 200000
#define DD 128
#define HH 256

typedef __attribute__((ext_vector_type(8))) short short8;
typedef __attribute__((ext_vector_type(4))) float f32x4;

__device__ inline float bflo(unsigned int u) {
    union { unsigned int u; float f; } x; x.u = u << 16; return x.f;
}
__device__ inline float bfhi(unsigned int u) {
    union { unsigned int u; float f; } x; x.u = u & 0xffff0000u; return x.f;
}
__device__ inline unsigned short f2b(float f) {  // RNE f32->bf16
    union { float f; unsigned int u; } x; x.f = f;
    unsigned int r = x.u + 0x7fffu + ((x.u >> 16) & 1u);
    return (unsigned short)(r >> 16);
}

// ---------------- CSR build ----------------
__global__ void k_hist(const int* __restrict__ src, const int* __restrict__ dst,
                       int* __restrict__ deg_d, int* __restrict__ deg_p) {
    int i = blockIdx.x * blockDim.x + threadIdx.x;
    if (i < NE) {
        atomicAdd(&deg_p[dst[i]], 1);
        atomicAdd(&deg_d[src[i]], 1);
    }
}

// merged dual scan: block 0 -> (degA,...), block 1 -> (degB,...)
__global__ void k_scan2(const int* __restrict__ degA, int* __restrict__ rowA,
                        int* __restrict__ curA, int nA,
                        const int* __restrict__ degB, int* __restrict__ rowB,
                        int* __restrict__ curB, int nB) {
    __shared__ int s[1024];
    const int* deg; int* rowptr; int* cursor; int n;
    if (blockIdx.x == 0) { deg = degA; rowptr = rowA; cursor = curA; n = nA; }
    else                 { deg = degB; rowptr = rowB; cursor = curB; n = nB; }
    const int t = threadIdx.x;
    const int chunk = (n + 1023) / 1024;
    const int lo = t * chunk;
    const int hi = min(n, lo + chunk);
    int local = 0;
    for (int i = lo; i < hi; ++i) local += deg[i];
    s[t] = local;
    __syncthreads();
    for (int off = 1; off < 1024; off <<= 1) {
        int v = (t >= off) ? s[t - off] : 0;
        __syncthreads();
        s[t] += v;
        __syncthreads();
    }
    int base = s[t] - local;
    for (int i = lo; i < hi; ++i) {
        rowptr[i] = base;
        cursor[i] = base;
        base += deg[i];
    }
    if (t == 1023) rowptr[n] = s[1023];
}

__global__ void k_fill(const int* __restrict__ src, const int* __restrict__ dst,
                       int* __restrict__ cur_p, int* __restrict__ cur_d,
                       int* __restrict__ csr_p, int* __restrict__ csr_d) {
    int i = blockIdx.x * blockDim.x + threadIdx.x;
    if (i < NE) {
        int s = src[i], d = dst[i];
        csr_p[atomicAdd(&cur_p[d], 1)] = s;
        csr_d[atomicAdd(&cur_d[s], 1)] = d;
    }
}

// ---------------- merged f32 -> bf16 convert (both feature tables) ----------------
__global__ void k_f2b2(const float* __restrict__ a, unsigned short* __restrict__ oa, int n4a,
                       const float* __restrict__ b, unsigned short* __restrict__ ob, int n4b) {
    int i = blockIdx.x * blockDim.x + threadIdx.x;
    if (i < n4a) {
        float4 v = ((const float4*)a)[i];
        ushort4 o; o.x = f2b(v.x); o.y = f2b(v.y); o.z = f2b(v.z); o.w = f2b(v.w);
        ((ushort4*)oa)[i] = o;
    } else if (i - n4a < n4b) {
        int j = i - n4a;
        float4 v = ((const float4*)b)[j];
        ushort4 o; o.x = f2b(v.x); o.y = f2b(v.y); o.z = f2b(v.z); o.w = f2b(v.w);
        ((ushort4*)ob)[j] = o;
    }
}

// ---------------- weight transpose+convert: dst[n][k] = bf16(src[k][n]) ----------------
struct WtD { const float* src; unsigned short* dst; int kbits; };
struct WtPack { WtD d[14]; };
__global__ void k_wt(WtPack p) {
    WtD d = p.d[blockIdx.y];
    const int K = 1 << d.kbits;
    int i = blockIdx.x * blockDim.x + threadIdx.x;
    if (i < 256 * K) {
        int nn = i >> d.kbits, k = i & (K - 1);
        d.dst[i] = f2b(d.src[k * 256 + nn]);
    }
}

// ---------------- merged dual-side bf16 CSR aggregate: 1 wave per dst node ----------------
struct ASide { const unsigned short* x; const int* rowptr; const int* idx;
               unsigned short* agg; int n; };

__global__ void k_agg2_128(ASide s0, ASide s1) {
    ASide S; int b;
    int bi = blockIdx.x;
    if (bi < s0.n) { S = s0; b = bi; } else { S = s1; b = bi - s0.n; }
    const int t = threadIdx.x;
    const int s = S.rowptr[b], e = S.rowptr[b + 1];
    float a0 = 0.f, a1 = 0.f;
    int j = s;
    for (; j + 1 < e; j += 2) {
        unsigned int u = *(const unsigned int*)(S.x + (size_t)S.idx[j] * 128 + 2 * t);
        unsigned int v = *(const unsigned int*)(S.x + (size_t)S.idx[j + 1] * 128 + 2 * t);
        a0 += bflo(u) + bflo(v);
        a1 += bfhi(u) + bfhi(v);
    }
    if (j < e) {
        unsigned int u = *(const unsigned int*)(S.x + (size_t)S.idx[j] * 128 + 2 * t);
        a0 += bflo(u); a1 += bfhi(u);
    }
    S.agg[(size_t)b * 128 + 2 * t]     = f2b(a0);
    S.agg[(size_t)b * 128 + 2 * t + 1] = f2b(a1);
}

__global__ void k_agg2_256(ASide s0, ASide s1) {
    ASide S; int b;
    int bi = blockIdx.x;
    if (bi < s0.n) { S = s0; b = bi; } else { S = s1; b = bi - s0.n; }
    const int t = threadIdx.x;
    const int s = S.rowptr[b], e = S.rowptr[b + 1];
    float a0 = 0.f, a1 = 0.f, a2 = 0.f, a3 = 0.f;
    int j = s;
    for (; j + 1 < e; j += 2) {
        uint2 u = *(const uint2*)(S.x + (size_t)S.idx[j] * 256 + 4 * t);
        uint2 v = *(const uint2*)(S.x + (size_t)S.idx[j + 1] * 256 + 4 * t);
        a0 += bflo(u.x) + bflo(v.x);
        a1 += bfhi(u.x) + bfhi(v.x);
        a2 += bflo(u.y) + bflo(v.y);
        a3 += bfhi(u.y) + bfhi(v.y);
    }
    if (j < e) {
        uint2 u = *(const uint2*)(S.x + (size_t)S.idx[j] * 256 + 4 * t);
        a0 += bflo(u.x); a1 += bfhi(u.x); a2 += bflo(u.y); a3 += bfhi(u.y);
    }
    S.agg[(size_t)b * 256 + 4 * t]     = f2b(a0);
    S.agg[(size_t)b * 256 + 4 * t + 1] = f2b(a1);
    S.agg[(size_t)b * 256 + 4 * t + 2] = f2b(a2);
    S.agg[(size_t)b * 256 + 4 * t + 3] = f2b(a3);
}

// ---------------- merged dual-side MFMA bf16 GEMM ----------------
// BM=64, BN=256 (full width, no grid.y), BK=32, 256 threads = 4 waves.
// Wave w owns cols [64w,64w+64); acc[i][j]: m-tile i(4) x n-tile j(4).
// A/B frag: lane l holds [m|n = l&15][k = 8*(l>>4)+e]; D: [row=4*(l>>4)+r][col=l&15].
struct GSide { const unsigned short* A1; const unsigned short* W1t;
               const unsigned short* A2; const unsigned short* W2t;
               const float* bias; float* outF; unsigned short* outB; int n; };

__global__ __launch_bounds__(256)
void k_mgemm2(GSide s0, GSide s1, int nblk0, int K1, int K2, int act) {
    __shared__ short As[64][40];    // 80B row stride: conflict-benign b128 reads
    __shared__ short Bs[256][40];

    GSide S;
    int bx;
    if ((int)blockIdx.x < nblk0) { S = s0; bx = blockIdx.x; }
    else                          { S = s1; bx = blockIdx.x - nblk0; }

    const int tid = threadIdx.x;
    const int w = tid >> 6, l = tid & 63;
    const int m16 = l & 15, kg = l >> 4;
    const int row0 = bx * 64;

    const f32x4 z4 = {0.f, 0.f, 0.f, 0.f};
    f32x4 acc[4][4];
#pragma unroll
    for (int i = 0; i < 4; ++i)
#pragma unroll
        for (int j = 0; j < 4; ++j) acc[i][j] = z4;

    for (int pass = 0; pass < 2; ++pass) {
        const unsigned short* A  = pass ? S.A2 : S.A1;
        const unsigned short* Wt = pass ? S.W2t : S.W1t;
        const int K = pass ? K2 : K1;
        if (A == nullptr) continue;
        for (int k0 = 0; k0 < K; k0 += 32) {
            {
                const int ar = tid >> 2, ac = (tid & 3) * 8;
                const int gr = row0 + ar;
                short8 v = {0, 0, 0, 0, 0, 0, 0, 0};
                if (gr < S.n) v = *(const short8*)(A + (size_t)gr * K + k0 + ac);
                *(short8*)&As[ar][ac] = v;
#pragma unroll
                for (int h = 0; h < 4; ++h)
                    *(short8*)&Bs[ar + 64 * h][ac] =
                        *(const short8*)(Wt + (size_t)(ar + 64 * h) * K + k0 + ac);
            }
            __syncthreads();
            short8 af[4];
#pragma unroll
            for (int i = 0; i < 4; ++i) af[i] = *(const short8*)&As[16 * i + m16][8 * kg];
#pragma unroll
            for (int j = 0; j < 4; ++j) {
                short8 bf = *(const short8*)&Bs[64 * w + 16 * j + m16][8 * kg];
#pragma unroll
                for (int i = 0; i < 4; ++i)
                    acc[i][j] = __builtin_amdgcn_mfma_f32_16x16x32_bf16(af[i], bf, acc[i][j], 0, 0, 0);
            }
            __syncthreads();
        }
    }

#pragma unroll
    for (int j = 0; j < 4; ++j) {
        const int gc = 64 * w + 16 * j + m16;
        const float bv = S.bias ? S.bias[gc] : 0.f;
#pragma unroll
        for (int i = 0; i < 4; ++i) {
#pragma unroll
            for (int r = 0; r < 4; ++r) {
                const int gr = row0 + 16 * i + 4 * kg + r;
                if (gr < S.n) {
                    float v = acc[i][j][r] + bv;
                    if (act) v = tanhf(v);
                    if (S.outF) S.outF[(size_t)gr * HH + gc] = v;
                    if (S.outB) S.outB[(size_t)gr * HH + gc] = f2b(v);
                }
            }
        }
    }
}

// ---------------- link decoder: one wave per link, bf16 pair-gather ----------------
__global__ void k_decode(const unsigned short* __restrict__ Ab, const unsigned short* __restrict__ Bb,
                         const int* __restrict__ rows, const int* __restrict__ cols,
                         const float* __restrict__ W2, const float* __restrict__ b2,
                         float* __restrict__ out) {
    const int wid = (blockIdx.x * blockDim.x + threadIdx.x) >> 6;
    const int lane = threadIdx.x & 63;
    if (wid >= NL) return;
    const int r = rows[wid], c = cols[wid];
    uint2 ua = *(const uint2*)(Ab + (size_t)r * HH + 4 * lane);
    uint2 ub = *(const uint2*)(Bb + (size_t)c * HH + 4 * lane);
    float4 wv = *(const float4*)(W2 + 4 * lane);
    float s = fmaxf(bflo(ua.x) + bflo(ub.x), 0.f) * wv.x +
              fmaxf(bfhi(ua.x) + bfhi(ub.x), 0.f) * wv.y +
              fmaxf(bflo(ua.y) + bflo(ub.y), 0.f) * wv.z +
              fmaxf(bfhi(ua.y) + bfhi(ub.y), 0.f) * wv.w;
#pragma unroll
    for (int off = 32; off > 0; off >>= 1) s += __shfl_xor(s, off, 64);
    if (lane == 0) out[wid] = s + b2[0];
}

extern "C" void kernel_launch(void* const* d_in, const int* in_sizes, int n_in,
                              void* d_out, int out_size, void* d_ws, size_t ws_size,
                              hipStream_t stream) {
    const float* x_drug  = (const float*)d_in[0];
    const float* x_prot  = (const float*)d_in[1];
    const int*   ei_src  = (const int*)d_in[2];
    const int*   ei_dst  = (const int*)d_in[3];
    const int*   eli_row = (const int*)d_in[4];
    const int*   eli_col = (const int*)d_in[5];
    const float* Wl_in_dp  = (const float*)d_in[6];
    const float* bl_in_dp  = (const float*)d_in[7];
    const float* Wr_in_dp  = (const float*)d_in[8];
    const float* Wl_in_pd  = (const float*)d_in[9];
    const float* bl_in_pd  = (const float*)d_in[10];
    const float* Wr_in_pd  = (const float*)d_in[11];
    const float* Wl_med_dp = (const float*)d_in[12];
    const float* bl_med_dp = (const float*)d_in[13];
    const float* Wr_med_dp = (const float*)d_in[14];
    const float* Wl_med_pd = (const float*)d_in[15];
    const float* bl_med_pd = (const float*)d_in[16];
    const float* Wr_med_pd = (const float*)d_in[17];
    const float* Wl_out_dp = (const float*)d_in[18];
    const float* bl_out_dp = (const float*)d_in[19];
    const float* Wr_out_dp = (const float*)d_in[20];
    const float* Wl_out_pd = (const float*)d_in[21];
    const float* bl_out_pd = (const float*)d_in[22];
    const float* Wr_out_pd = (const float*)d_in[23];
    const float* W1 = (const float*)d_in[24];
    const float* b1 = (const float*)d_in[25];
    const float* W2 = (const float*)d_in[26];
    const float* b2 = (const float*)d_in[27];

    char* ws = (char*)d_ws;
    size_t off = 0;
    auto alloc = [&](size_t bytes) {
        void* p = ws + off;
        off = (off + bytes + 255) & ~(size_t)255;
        return p;
    };

    int* deg_p    = (int*)alloc((size_t)NP * 4);
    int* deg_d    = (int*)alloc((size_t)ND * 4);
    int* rowptr_p = (int*)alloc((size_t)(NP + 1) * 4);
    int* rowptr_d = (int*)alloc((size_t)(ND + 1) * 4);
    int* cur_p    = (int*)alloc((size_t)NP * 4);
    int* cur_d    = (int*)alloc((size_t)ND * 4);
    int* csr_p    = (int*)alloc((size_t)NE * 4);
    int* csr_d    = (int*)alloc((size_t)NE * 4);

    unsigned short* wt[14];
    const int kk[14] = {128,128,128,128, 256,256,256,256, 256,256,256,256, 256,256};
    for (int i = 0; i < 14; ++i) wt[i] = (unsigned short*)alloc((size_t)256 * kk[i] * 2);

    unsigned short* xdbf = (unsigned short*)alloc((size_t)ND * DD * 2);
    unsigned short* xpbf = (unsigned short*)alloc((size_t)NP * DD * 2);
    unsigned short* xd_a = (unsigned short*)alloc((size_t)ND * HH * 2);
    unsigned short* xd_b = (unsigned short*)alloc((size_t)ND * HH * 2);
    unsigned short* xp_a = (unsigned short*)alloc((size_t)NP * HH * 2);
    unsigned short* xp_b = (unsigned short*)alloc((size_t)NP * HH * 2);
    unsigned short* aggd = (unsigned short*)alloc((size_t)ND * HH * 2);
    unsigned short* aggp = (unsigned short*)alloc((size_t)NP * HH * 2);
    unsigned short* zdbf = (unsigned short*)alloc((size_t)ND * HH * 2);
    unsigned short* zpbf = (unsigned short*)alloc((size_t)NP * HH * 2);

    float* zd   = (float*)d_out;
    float* zp   = zd + (size_t)ND * HH;
    float* outv = zp + (size_t)NP * HH;

    const int nbD = (ND + 63) / 64;   // 313
    const int nbP = (NP + 63) / 64;   // 125
    const dim3 gG(nbD + nbP);         // merged GEMM grid (438)
    const dim3 gA(NP + ND);           // merged aggregate grid (28000)

    // ---- CSR build ----
    hipMemsetAsync(deg_p, 0, (size_t)NP * 4, stream);
    hipMemsetAsync(deg_d, 0, (size_t)ND * 4, stream);
    k_hist<<<(NE + 255) / 256, 256, 0, stream>>>(ei_src, ei_dst, deg_d, deg_p);
    k_scan2<<<2, 1024, 0, stream>>>(deg_p, rowptr_p, cur_p, NP,
                                    deg_d, rowptr_d, cur_d, ND);
    k_fill<<<(NE + 255) / 256, 256, 0, stream>>>(ei_src, ei_dst, cur_p, cur_d, csr_p, csr_d);

    // ---- input/weight conversion ----
    k_f2b2<<<(ND * DD / 4 + NP * DD / 4 + 255) / 256, 256, 0, stream>>>(
        x_drug, xdbf, ND * DD / 4, x_prot, xpbf, NP * DD / 4);
    {
        WtPack p;
        const float* src[14] = {Wl_in_dp, Wr_in_dp, Wl_in_pd, Wr_in_pd,
                                Wl_med_dp, Wr_med_dp, Wl_med_pd, Wr_med_pd,
                                Wl_out_dp, Wr_out_dp, Wl_out_pd, Wr_out_pd,
                                W1, W1 + (size_t)HH * HH};
        for (int i = 0; i < 14; ++i) {
            p.d[i].src = src[i];
            p.d[i].dst = wt[i];
            p.d[i].kbits = (kk[i] == 128) ? 7 : 8;
        }
        k_wt<<<dim3(256, 14), 256, 0, stream>>>(p);
    }

    // side structs: P-aggregate gathers drug rows for proteins; D-aggregate the reverse
    ASide aP128 = {xdbf, rowptr_p, csr_p, aggp, NP};
    ASide aD128 = {xpbf, rowptr_d, csr_d, aggd, ND};

    // ---- layer in (K=128), tanh -> xp_a/xd_a ----
    k_agg2_128<<<gA, 64, 0, stream>>>(aP128, aD128);
    {
        GSide d = {aggd, wt[2], xdbf, wt[3], bl_in_pd, nullptr, xd_a, ND};
        GSide pS = {aggp, wt[0], xpbf, wt[1], bl_in_dp, nullptr, xp_a, NP};
        k_mgemm2<<<gG, 256, 0, stream>>>(d, pS, nbD, 128, 128, 1);
    }

    // ---- med layer 1 -> xp_b/xd_b ----
    {
        ASide aP = {xd_a, rowptr_p, csr_p, aggp, NP};
        ASide aD = {xp_a, rowptr_d, csr_d, aggd, ND};
        k_agg2_256<<<gA, 64, 0, stream>>>(aP, aD);
        GSide d = {aggd, wt[6], xd_a, wt[7], bl_med_pd, nullptr, xd_b, ND};
        GSide pS = {aggp, wt[4], xp_a, wt[5], bl_med_dp, nullptr, xp_b, NP};
        k_mgemm2<<<gG, 256, 0, stream>>>(d, pS, nbD, 256, 256, 1);
    }

    // ---- med layer 2 -> xp_a/xd_a ----
    {
        ASide aP = {xd_b, rowptr_p, csr_p, aggp, NP};
        ASide aD = {xp_b, rowptr_d, csr_d, aggd, ND};
        k_agg2_256<<<gA, 64, 0, stream>>>(aP, aD);
        GSide d = {aggd, wt[6], xd_b, wt[7], bl_med_pd, nullptr, xd_a, ND};
        GSide pS = {aggp, wt[4], xp_b, wt[5], bl_med_dp, nullptr, xp_a, NP};
        k_mgemm2<<<gG, 256, 0, stream>>>(d, pS, nbD, 256, 256, 1);
    }

    // ---- layer out (no act): f32 -> d_out, bf16 -> zdbf/zpbf ----
    {
        ASide aP = {xd_a, rowptr_p, csr_p, aggp, NP};
        ASide aD = {xp_a, rowptr_d, csr_d, aggd, ND};
        k_agg2_256<<<gA, 64, 0, stream>>>(aP, aD);
        GSide d = {aggd, wt[10], xd_a, wt[11], bl_out_pd, zd, zdbf, ND};
        GSide pS = {aggp, wt[8], xp_a, wt[9], bl_out_dp, zp, zpbf, NP};
        k_mgemm2<<<gG, 256, 0, stream>>>(d, pS, nbD, 256, 256, 0);
    }

    // ---- decoder: A = zd@W1_top -> xd_b, B = zp@W1_bot + b1 -> xp_b (relu in k_decode) ----
    {
        GSide d = {zdbf, wt[12], nullptr, nullptr, nullptr, nullptr, xd_b, ND};
        GSide pS = {zpbf, wt[13], nullptr, nullptr, b1, nullptr, xp_b, NP};
        k_mgemm2<<<gG, 256, 0, stream>>>(d, pS, nbD, 256, 256, 0);
    }
    k_decode<<<(NL + 3) / 4, 256, 0, stream>>>(xd_b, xp_b, eli_row, eli_col, W2, b2, outv);
}